// Round 6
// baseline (221.127 us; speedup 1.0000x reference)
//
#include <hip/hip_runtime.h>
#include <math.h>

#define DD   128
#define DI   170
#define BB   4096
#define NNEG 5
#define ROWS 8
#define NBLK (BB / ROWS)            // 512 blocks x 8 waves = 16 waves/CU
#define SQRT_D 11.3137084989847603904f   // sqrt(128)

__device__ __forceinline__ float wave_bcast_sum(float v) {
#pragma unroll
    for (int m = 1; m < 64; m <<= 1) v += __shfl_xor(v, m, 64);
    return v;
}

// Prep: inverse L2 norms. Blocks 0..84: W_hidden/W_gate row norms (4 each).
// Block 85: W_ff_out column norms (coalesced row-walk) + zero the output.
__global__ __launch_bounds__(256) void norms_kernel(
    const float* __restrict__ W_hidden,
    const float* __restrict__ W_gate,
    const float* __restrict__ W_ff_out,
    float* __restrict__ inv_h,
    float* __restrict__ inv_g,
    float* __restrict__ inv_f,
    float* __restrict__ out)
{
    if (blockIdx.x < 85) {
        const int wave = threadIdx.x >> 6;
        const int lane = threadIdx.x & 63;
        const int v = blockIdx.x * 4 + wave;          // 0 .. 339
        const float* W = (v < DI) ? W_hidden : W_gate;
        const int row = (v < DI) ? v : v - DI;
        float2 p = ((const float2*)(W + (long)row * DD))[lane];
        float s = wave_bcast_sum(p.x * p.x + p.y * p.y);
        if (lane == 0) {
            float inv = rsqrtf(s);
            if (v < DI) inv_h[row] = inv; else inv_g[row] = inv;
        }
    } else {
        if (threadIdx.x == 0) out[0] = 0.0f;
        const int c = threadIdx.x;                    // column of W_ff_out (D x DI)
        if (c < DI) {
            float s = 0.0f;
#pragma unroll 4
            for (int d = 0; d < DD; ++d) {
                float a = W_ff_out[(long)d * DI + c]; // coalesced across threads
                s += a * a;
            }
            inv_f[c] = rsqrtf(s);
        }
    }
}

// Fused main kernel, 512 threads/block. Same grid + same weight access
// patterns as the best-measured R2 variant, but every serial chain is cut
// ~in half by splitting it across twice the threads:
//  P1: 8 waves, one emb row each.
//  P2: (i, dh) = (tid%170, tid/170): each thread walks HALF the d-range
//      (16 iters, manual prefetch); partials combined via LDS.
//  P2b: (dd, ih, rq): each thread walks HALF the i-range (43 iters).
//  P3: wave w owns row w: 6 parked logit chains, x loaded once.
__global__ __launch_bounds__(512) void main_kernel(
    const int*   __restrict__ input_ids,
    const int*   __restrict__ target_ids,
    const int*   __restrict__ neg_ids,
    const float* __restrict__ W_in,
    const float* __restrict__ W_out,
    const float* __restrict__ W_hidden,
    const float* __restrict__ W_gate,
    const float* __restrict__ W_ff_out,
    const float* __restrict__ hidden_scale,
    const float* __restrict__ gate_scale,
    const float* __restrict__ logit_scale,
    const float* __restrict__ inv_h,
    const float* __restrict__ inv_g,
    const float* __restrict__ inv_f,
    float* __restrict__ out)
{
    __shared__ __align__(16) float s_emb[ROWS][132];       // 4.2 KB
    __shared__ __align__(16) float s_x[ROWS][172];         // 5.5 KB
    __shared__ __align__(16) float s_pah[ROWS][172];       // 5.5 KB
    __shared__ __align__(16) float s_pag[ROWS][172];       // 5.5 KB
    __shared__ __align__(16) float s_p2b[2][ROWS][DD];     // 8 KB
    __shared__ float s_red[8];

    const int tid  = threadIdx.x;
    const int wave = tid >> 6;
    const int lane = tid & 63;
    const int b0   = blockIdx.x * ROWS;

    // ---- Phase 1: wave w gathers + l2-normalizes emb row w ----
    {
        const int id = input_ids[b0 + wave];               // wave-uniform
        float2 p = ((const float2*)(W_in + (long)id * DD))[lane];
        float s = wave_bcast_sum(p.x * p.x + p.y * p.y);
        float inv = rsqrtf(s);
        s_emb[wave][2 * lane]     = p.x * inv;
        s_emb[wave][2 * lane + 1] = p.y * inv;
    }
    __syncthreads();

    // ---- Phase 2: half-d walk per thread, R2's proven own-row access ----
    const int pi = tid % DI;       // 0..169
    const int dh = tid / DI;       // 0,1 active; 2 idle (tid >= 340)
    float ah[ROWS], ag[ROWS];
#pragma unroll
    for (int r = 0; r < ROWS; ++r) { ah[r] = 0.0f; ag[r] = 0.0f; }
    if (dh < 2) {
        const float4* wh = (const float4*)(W_hidden + (long)pi * DD) + dh * 16;
        const float4* wg = (const float4*)(W_gate   + (long)pi * DD) + dh * 16;
        const int base = dh * 16;
        float4 hc = wh[0], gc = wg[0];
#pragma unroll
        for (int k = 0; k < 16; ++k) {
            float4 hn, gn;
            if (k < 15) { hn = wh[k + 1]; gn = wg[k + 1]; }   // prefetch next
#pragma unroll
            for (int r = 0; r < ROWS; ++r) {
                float4 e4 = *(const float4*)&s_emb[r][4 * (base + k)];  // broadcast
                ah[r] += e4.x * hc.x + e4.y * hc.y + e4.z * hc.z + e4.w * hc.w;
                ag[r] += e4.x * gc.x + e4.y * gc.y + e4.z * gc.z + e4.w * gc.w;
            }
            hc = hn; gc = gn;
        }
        if (dh == 1) {
#pragma unroll
            for (int r = 0; r < ROWS; ++r) {
                s_pah[r][pi] = ah[r];
                s_pag[r][pi] = ag[r];
            }
        }
    }
    __syncthreads();

    if (dh == 0) {                 // tid < 170: combine halves, silu, write x
        const float hs = hidden_scale[pi] * inv_h[pi];
        const float gs = gate_scale[pi]   * inv_g[pi] * SQRT_D;
        const float fi = inv_f[pi];
#pragma unroll
        for (int r = 0; r < ROWS; ++r) {
            const float h = (ah[r] + s_pah[r][pi]) * hs;
            const float g = (ag[r] + s_pag[r][pi]) * gs;
            const float x = (g / (1.0f + __expf(-g))) * h;   // silu(g) * h
            s_x[r][pi] = x * fi;
        }
    }
    __syncthreads();

    // ---- Phase 2b: half-i walk per thread ----
    {
        const int dd = tid & 127;
        const int ih = (tid >> 7) & 1;
        const int rq = tid >> 8;                 // rows rq*4 .. rq*4+3
        const int n2 = ih ? 42 : 43;             // float2 count (85 total)
        const int ibase = ih * 86;               // float offset (8B-aligned)
        float acc[4] = {0.f, 0.f, 0.f, 0.f};
        const float2* wrow = (const float2*)(W_ff_out + (long)dd * DI) + ih * 43;
#pragma unroll 7
        for (int i2 = 0; i2 < n2; ++i2) {
            float2 wf = wrow[i2];
#pragma unroll
            for (int j = 0; j < 4; ++j) {
                float2 xv = *(const float2*)&s_x[rq * 4 + j][ibase + 2 * i2];
                acc[j] += xv.x * wf.x + xv.y * wf.y;
            }
        }
#pragma unroll
        for (int j = 0; j < 4; ++j) s_p2b[ih][rq * 4 + j][dd] = acc[j];
    }
    __syncthreads();

    // ---- Phase 3: wave w owns row w: 6 parked logit chains ----
    {
        const int r = wave;
        const float x0 = s_p2b[0][r][lane]      + s_p2b[1][r][lane];
        const float x1 = s_p2b[0][r][64 + lane] + s_p2b[1][r][64 + lane];
        int ids6[6];
        ids6[0] = target_ids[b0 + r];
#pragma unroll
        for (int k = 1; k < 6; ++k) ids6[k] = neg_ids[(b0 + r) * NNEG + k - 1];
        float w0[6], w1[6], lsc[6];
#pragma unroll
        for (int k = 0; k < 6; ++k) {
            const float* wrow = W_out + (long)ids6[k] * DD;
            w0[k]  = wrow[lane];
            w1[k]  = wrow[64 + lane];
            lsc[k] = logit_scale[ids6[k]];
        }
        float wacc = 0.0f;
#pragma unroll
        for (int k = 0; k < 6; ++k) {
            float dot = w0[k] * x0 + w1[k] * x1;
            float ss  = w0[k] * w0[k] + w1[k] * w1[k];
#pragma unroll
            for (int m = 1; m < 64; m <<= 1) {
                dot += __shfl_xor(dot, m, 64);
                ss  += __shfl_xor(ss,  m, 64);
            }
            const float logit = dot * rsqrtf(ss) * lsc[k] * SQRT_D;
            const float z  = (k == 0) ? logit : -logit;
            const float ls = fminf(z, 0.0f) - log1pf(__expf(-fabsf(z)));  // stable log_sigmoid
            wacc += (k == 0) ? ls * (1.0f / BB) : ls * (1.0f / (BB * NNEG));
        }
        if (lane == 0) s_red[wave] = wacc;
    }
    __syncthreads();
    if (tid == 0) {
        float tot = 0.0f;
#pragma unroll
        for (int w = 0; w < 8; ++w) tot += s_red[w];
        atomicAdd(out, -tot);
    }
}

extern "C" void kernel_launch(void* const* d_in, const int* in_sizes, int n_in,
                              void* d_out, int out_size, void* d_ws, size_t ws_size,
                              hipStream_t stream) {
    (void)in_sizes; (void)n_in; (void)out_size; (void)ws_size;
    const int*   input_ids    = (const int*)  d_in[0];
    const int*   target_ids   = (const int*)  d_in[1];
    const int*   neg_ids      = (const int*)  d_in[2];
    const float* W_in         = (const float*)d_in[3];
    const float* W_out        = (const float*)d_in[4];
    const float* W_hidden     = (const float*)d_in[5];
    const float* W_gate       = (const float*)d_in[6];
    const float* W_ff_out     = (const float*)d_in[7];
    const float* hidden_scale = (const float*)d_in[8];
    const float* gate_scale   = (const float*)d_in[9];
    const float* logit_scale  = (const float*)d_in[10];
    float* out   = (float*)d_out;
    float* inv_h = (float*)d_ws;
    float* inv_g = inv_h + DI;
    float* inv_f = inv_g + DI;

    norms_kernel<<<86, 256, 0, stream>>>(W_hidden, W_gate, W_ff_out,
                                         inv_h, inv_g, inv_f, out);
    main_kernel<<<NBLK, 512, 0, stream>>>(input_ids, target_ids, neg_ids,
                                          W_in, W_out, W_hidden, W_gate, W_ff_out,
                                          hidden_scale, gate_scale, logit_scale,
                                          inv_h, inv_g, inv_f, out);
}